// Round 1
// baseline (406.519 us; speedup 1.0000x reference)
//
#include <hip/hip_runtime.h>
#include <math.h>

static constexpr int BT  = 512;    // batch
static constexpr int TT  = 2048;   // time steps
static constexpr int NCH = BT * 8; // 4096 chains

// f64-derived constants, cast to f32 exactly as the reference does
static constexpr float C00 = (float)(1000.0 / (1.0 - 0.09));            // D[0][0]
static constexpr float C01 = (float)((1000.0 / (1.0 - 0.09)) * 0.3);    // D[0][1]
static constexpr float C22 = (float)((1000.0 / (1.0 - 0.09)) * 0.35);   // D[2][2]
static constexpr float INV3GH = (float)(1.0 / (3.0 * (1000.0 / 2.6) + 100.0));

__device__ __forceinline__ float softplus_f(float v) {
    return fmaxf(v, 0.0f) + log1pf(expf(-fabsf(v)));
}

// K1: projections + damage candidate. One thread per (b,t).
// Writes arr[t][chain] = (d_new, De_xx, De_yy, De_xy), chain = b*8+p.
__global__ __launch_bounds__(256) void k_proj(
    const float* __restrict__ x, const float* __restrict__ W11,
    const float* __restrict__ W12, float4* __restrict__ arr)
{
    __shared__ float w11s[512];   // 16 x 32
    __shared__ float w12d[768];   // 24 x 32, D folded in
    int tid = threadIdx.x;
    for (int i = tid; i < 512; i += 256) w11s[i] = W11[i];
    for (int i = tid; i < 768; i += 256) {
        int r = i >> 5, fc = i & 31;
        int p = r / 3, j = r - p * 3;
        const float* wb = W12 + p * 96 + fc;  // row 3p, col fc
        float v;
        if (j == 0)      v = C00 * wb[0]  + C01 * wb[32];
        else if (j == 1) v = C01 * wb[0]  + C00 * wb[32];
        else             v = C22 * wb[64];
        w12d[i] = v;
    }
    __syncthreads();

    int gid = blockIdx.x * 256 + tid;
    int b = gid & (BT - 1), t = gid >> 9;

    const float4* xv = (const float4*)(x + ((size_t)b * TT + t) * 32);
    float xr[32];
    #pragma unroll
    for (int i = 0; i < 8; ++i) {
        float4 X = xv[i];
        xr[4*i+0] = X.x; xr[4*i+1] = X.y; xr[4*i+2] = X.z; xr[4*i+3] = X.w;
    }

    float4* op = arr + ((size_t)t * NCH + b * 8);
    #pragma unroll
    for (int p = 0; p < 8; ++p) {
        float dn = 0.f, ds = 0.f, e0 = 0.f, e1 = 0.f, e2 = 0.f;
        const float* wa = w11s + p * 64;
        const float* wb = w12d + p * 96;
        #pragma unroll
        for (int f = 0; f < 32; ++f) {
            float xf = xr[f];
            dn = fmaf(xf, wa[f],      dn);
            ds = fmaf(xf, wa[32 + f], ds);
            e0 = fmaf(xf, wb[f],      e0);
            e1 = fmaf(xf, wb[32 + f], e1);
            e2 = fmaf(xf, wb[64 + f], e2);
        }
        float dnp = fmaxf(dn, 0.f);
        float lam = sqrtf(fmaf(dnp, dnp, fmaf(ds, ds, 1e-12f)));
        float dnew = (0.1f * (lam - 0.01f)) / (lam * 0.09f);
        dnew = fminf(fmaxf(dnew, 0.f), 1.f);
        op[p] = make_float4(dnew, e0, e1, e2);
    }
}

// K2: the sequential scan. One lane per chain (4096 lanes total).
// State: d (damage), P = D*eps_p (3), kappa. Writes damaged stress
// sig[b][t][p][3] (so each lane's t-stream fills HBM lines densely).
__global__ __launch_bounds__(64) void k_scan(
    const float4* __restrict__ a, float* __restrict__ sig)
{
    int chain = blockIdx.x * 64 + threadIdx.x;
    int b = chain >> 3, p = chain & 7;
    const float4* ap = a + chain;
    float* sp = sig + (size_t)b * (TT * 24) + p * 3;

    float d = 0.f, Pxx = 0.f, Pyy = 0.f, Pxy = 0.f, kap = 0.f;

    float4 cur[8];
    #pragma unroll
    for (int j = 0; j < 8; ++j) cur[j] = ap[j * NCH];

    for (int t = 0; t < TT; t += 8) {
        float4 nxt[8];
        #pragma unroll
        for (int j = 0; j < 8; ++j) {
            int tt = t + 8 + j; if (tt > TT - 1) tt = TT - 1;
            nxt[j] = ap[tt * NCH];
        }
        #pragma unroll
        for (int j = 0; j < 8; ++j) {
            float4 v = cur[j];
            bool loading = v.x > d;          // d_new > d_hist
            d = fmaxf(d, v.x);
            float sxx = v.y - Pxx, syy = v.z - Pyy, sxy = v.w - Pxy;
            float u2 = fmaf(syy, syy, 1e-12f);
            float q  = fmaf(sxx, sxx - syy, u2);
            q = fmaf(3.0f * sxy, sxy, q);
            float rq  = __builtin_amdgcn_rsqf(q);
            float seq = sqrtf(q);
            float sigY = fmaf(100.f, kap, 10.f);
            float dk = fmaxf(seq - sigY, 0.f) * INV3GH;
            kap += dk;
            float f = fminf(fmaf(100.f, dk, sigY) * rq, 1.f);
            Pxx = fmaf(f, Pxx - v.y, v.y);
            Pyy = fmaf(f, Pyy - v.z, v.z);
            Pxy = fmaf(f, Pxy - v.w, v.w);
            float scale = loading ? f : fmaf(-f, d, f);   // f or f*(1-d)
            float* so = sp + (t + j) * 24;
            so[0] = scale * sxx;
            so[1] = scale * syy;
            so[2] = scale * sxy;
        }
        #pragma unroll
        for (int j = 0; j < 8; ++j) cur[j] = nxt[j];
    }
}

// K3: out[b][t][:] = sig_row(24) @ softplus(W2)^T. One thread per (b,t).
__global__ __launch_bounds__(256) void k_out(
    const float* __restrict__ sig, const float* __restrict__ W2,
    float* __restrict__ out)
{
    __shared__ float w2s[144];
    int tid = threadIdx.x;
    if (tid < 144) w2s[tid] = softplus_f(W2[tid]);
    __syncthreads();

    int gid = blockIdx.x * 256 + tid;   // = b*2048 + t
    const float4* spv = (const float4*)(sig + (size_t)gid * 24);
    float s[24];
    #pragma unroll
    for (int i = 0; i < 6; ++i) {
        float4 v = spv[i];
        s[4*i] = v.x; s[4*i+1] = v.y; s[4*i+2] = v.z; s[4*i+3] = v.w;
    }
    float o[6];
    #pragma unroll
    for (int k = 0; k < 6; ++k) {
        float acc = 0.f;
        #pragma unroll
        for (int j = 0; j < 24; ++j) acc = fmaf(s[j], w2s[k * 24 + j], acc);
        o[k] = acc;
    }
    float2* ov = (float2*)(out + (size_t)gid * 6);
    ov[0] = make_float2(o[0], o[1]);
    ov[1] = make_float2(o[2], o[3]);
    ov[2] = make_float2(o[4], o[5]);
}

extern "C" void kernel_launch(void* const* d_in, const int* in_sizes, int n_in,
                              void* d_out, int out_size, void* d_ws, size_t ws_size,
                              hipStream_t stream)
{
    const float* x   = (const float*)d_in[0];
    const float* W11 = (const float*)d_in[1];
    const float* W12 = (const float*)d_in[2];
    const float* W2  = (const float*)d_in[3];
    float* out = (float*)d_out;

    float4* arr = (float4*)d_ws;                                   // 128 MiB
    float*  sig = (float*)((char*)d_ws + (size_t)TT * NCH * 16);   //  96 MiB

    hipLaunchKernelGGL(k_proj, dim3((BT * TT) / 256), dim3(256), 0, stream,
                       x, W11, W12, arr);
    hipLaunchKernelGGL(k_scan, dim3(NCH / 64), dim3(64), 0, stream, arr, sig);
    hipLaunchKernelGGL(k_out,  dim3((BT * TT) / 256), dim3(256), 0, stream,
                       sig, W2, out);
}